// Round 10
// baseline (529.550 us; speedup 1.0000x reference)
//
#include <hip/hip_runtime.h>
#include <stdint.h>

#define D_MODEL 1024
#define EXP_D   4096
#define NE      8
#define NTOK    8192
#define BMT     128
#define MAX_TILES 136
#define NS_MAX  17408   // MAX_TILES*128

typedef __attribute__((ext_vector_type(8))) short short8;
typedef __attribute__((ext_vector_type(4))) float f32x4;
typedef __attribute__((ext_vector_type(4))) unsigned short us4;

// ---- workspace layout (bytes) ----
#define WS_CURSORS   32         // int[8]  <- scatter accumulates counts here
#define WS_PADOFF    64         // int[16]
#define WS_META      128        // int[32], meta[0]=ntiles
#define WS_TILE_E    256        // int[256]
#define WS_PP        4096       // float[2048*8]
#define WS_TOP_E     69632      // int[16384]
#define WS_TOP_W     135168     // float[16384]
#define WS_TOK_RANK  200704     // int[16384]
#define WS_SLOT_W    270336     // float[17408]
#define WS_TOK_SLOT  339968     // int[16384]
#define WS_XG        405504     // bf16 [17408][1024]  (Yb aliases this)
#define WS_HB        36057088   // bf16 [17408][4096]
#define WS_WB        178663424  // bf16 [8][4096][1024] -> ends 245,772,288
#define WS_WB2       245772288  // bf16 [8][1024][4096] (only if ws big enough)
#define REQ_BIG      312881152ull

__device__ __forceinline__ unsigned short f2bf(float f){
  __bf16 h = (__bf16)f;
  return __builtin_bit_cast(unsigned short, h);
}
__device__ __forceinline__ float bf2f(unsigned short u){
  unsigned int v = ((unsigned int)u) << 16;
  return __builtin_bit_cast(float, v);
}
__device__ __forceinline__ void gl_lds16(const void* g, void* l){
  __builtin_amdgcn_global_load_lds((const __attribute__((address_space(1))) unsigned int*)g,
                                   (__attribute__((address_space(3))) unsigned int*)l,
                                   16, 0, 0);
}

template<int N> __device__ __forceinline__ void vmw(){
  if constexpr (N==0)      asm volatile("s_waitcnt vmcnt(0)" ::: "memory");
  else if constexpr (N==6) asm volatile("s_waitcnt vmcnt(6)" ::: "memory");
}

// ---------------- router (blocks 0..2047, NO atomics) + weight cvt (blocks >=2048) ----------------
__global__ __launch_bounds__(256) void router_cvt_kernel(
    const float* __restrict__ x, const float* __restrict__ Wr,
    const float* __restrict__ br,
    int* __restrict__ top_e, float* __restrict__ top_w,
    float* __restrict__ pp,
    const float* __restrict__ W1, unsigned short* __restrict__ Wb,
    const float* __restrict__ W2, unsigned short* __restrict__ W2b,
    int cvt_total4)
{
  const int tid = threadIdx.x;
  if ((int)blockIdx.x >= NTOK/4){
    const int n4 = NE*EXP_D*D_MODEL/4;
    const int stride = ((int)gridDim.x - NTOK/4)*256;
    for (int i = ((int)blockIdx.x - NTOK/4)*256 + tid; i < cvt_total4; i += stride){
      if (i < n4){
        const float4 v = *(const float4*)&W1[(size_t)i*4];
        us4 o; o[0]=f2bf(v.x); o[1]=f2bf(v.y); o[2]=f2bf(v.z); o[3]=f2bf(v.w);
        *(us4*)&Wb[(size_t)i*4] = o;
      } else {
        const int j = i - n4;
        const float4 v = *(const float4*)&W2[(size_t)j*4];
        us4 o; o[0]=f2bf(v.x); o[1]=f2bf(v.y); o[2]=f2bf(v.z); o[3]=f2bf(v.w);
        *(us4*)&W2b[(size_t)j*4] = o;
      }
    }
    return;
  }
  __shared__ float WrS[NE*D_MODEL];
  __shared__ float wprob[4][NE];
#pragma unroll
  for (int i=0;i<8;++i){
    int j = (tid + i*256)*4;
    *(float4*)&WrS[j] = *(const float4*)&Wr[j];
  }
  __syncthreads();
  const int w = tid>>6, lane = tid&63;
  const int t = blockIdx.x*4 + w;
  const float* xt = x + (size_t)t*D_MODEL;
  float accv[8] = {0,0,0,0,0,0,0,0};
#pragma unroll
  for (int i=0;i<4;++i){
    const int k = i*256 + lane*4;
    const float4 xv = *(const float4*)&xt[k];
#pragma unroll
    for (int e=0;e<8;++e){
      const float4 wv = *(const float4*)&WrS[e*D_MODEL + k];
      accv[e] += xv.x*wv.x + xv.y*wv.y + xv.z*wv.z + xv.w*wv.w;
    }
  }
#pragma unroll
  for (int m=32;m>0;m>>=1){
#pragma unroll
    for (int e=0;e<8;++e) accv[e] += __shfl_xor(accv[e], m, 64);
  }
  if (lane==0){
    float lg[8];
#pragma unroll
    for (int e=0;e<8;++e) lg[e] = accv[e] + br[e];
    float mx = lg[0];
#pragma unroll
    for (int e=1;e<8;++e) mx = fmaxf(mx, lg[e]);
    float p[8]; float s=0.f;
#pragma unroll
    for (int e=0;e<8;++e){ p[e] = __expf(lg[e]-mx); s += p[e]; }
    const float inv = 1.f/s;
#pragma unroll
    for (int e=0;e<8;++e){ p[e] *= inv; wprob[w][e] = p[e]; }
    int i1=0; float p1v=p[0];
#pragma unroll
    for (int e=1;e<8;++e) if (p[e] > p1v){ p1v=p[e]; i1=e; }
    int i2=-1; float p2v=-1.f;
#pragma unroll
    for (int e=0;e<8;++e) if (e!=i1 && p[e] > p2v){ p2v=p[e]; i2=e; }
    const float rn = 1.f/(p1v+p2v);
    top_e[2*t]   = i1; top_w[2*t]   = p1v*rn;
    top_e[2*t+1] = i2; top_w[2*t+1] = p2v*rn;
  }
  __syncthreads();
  if (tid<8){
    pp[blockIdx.x*8+tid] = wprob[0][tid]+wprob[1][tid]+wprob[2][tid]+wprob[3][tid];
  }
}

// ---------------- standalone cvt (fallback, W2) ----------------
__global__ __launch_bounds__(256) void cvt_kernel(const float* __restrict__ W,
                                                  unsigned short* __restrict__ Wb){
  const int n4 = NE*EXP_D*D_MODEL/4;
  for (int i = blockIdx.x*256 + threadIdx.x; i < n4; i += gridDim.x*256){
    const float4 v = *(const float4*)&W[(size_t)i*4];
    us4 o; o[0]=f2bf(v.x); o[1]=f2bf(v.y); o[2]=f2bf(v.z); o[3]=f2bf(v.w);
    *(us4*)&Wb[(size_t)i*4] = o;
  }
}

// ---------------- scatter: LDS-aggregated counting + expert-local ranks ----------------
__global__ __launch_bounds__(1024) void scatter_kernel(
    const int* __restrict__ top_e,
    int* __restrict__ cursors, int* __restrict__ tok_rank)
{
  __shared__ int cnt[NE];
  __shared__ int base[NE];
  const int tid = threadIdx.x;
  if (tid < NE) cnt[tid] = 0;
  __syncthreads();
  const int t = blockIdx.x*1024 + tid;
  const int e0 = top_e[2*t], e1 = top_e[2*t+1];
  const int p0 = atomicAdd(&cnt[e0], 1);
  const int p1 = atomicAdd(&cnt[e1], 1);
  __syncthreads();
  if (tid < NE) base[tid] = atomicAdd(&cursors[tid], cnt[tid]);
  __syncthreads();
  tok_rank[2*t]   = base[e0] + p0;
  tok_rank[2*t+1] = base[e1] + p1;
}

// ---------------- prefix (AFTER scatter): tile table + aux loss ----------------
__global__ __launch_bounds__(256) void prefix_kernel(int* __restrict__ wsI,
                                                     const float* __restrict__ pp,
                                                     float* __restrict__ aux_out){
  const int tid = threadIdx.x;
  int* counts = wsI + 8;    // cursors (= final per-expert counts after scatter)
  int* padoff = wsI + 16;
  int* meta   = wsI + 32;
  int* tileE  = wsI + 64;
  __shared__ int tileCum[9];
  __shared__ float dev2[8];
  if (tid==0){
    int nt = 0;
    tileCum[0] = 0;
    for (int e=0;e<NE;++e){
      padoff[e] = nt*BMT;
      nt += (counts[e] + BMT - 1) >> 7;
      tileCum[e+1] = nt;
    }
    meta[0] = nt;
  }
  __syncthreads();
  const int nt = tileCum[8];
  for (int i=tid; i<nt; i+=256){
    int e = 0;
    while (tileCum[e+1] <= i) ++e;
    tileE[i] = e;
  }
  const int ex = tid>>5, j = tid&31;
  float s = 0.f;
  for (int b=j; b<NTOK/4; b+=32) s += pp[b*8+ex];
#pragma unroll
  for (int m=16;m>0;m>>=1) s += __shfl_xor(s, m, 64);
  if (j==0){ float d = s*(1.f/(float)NTOK) - 0.125f; dev2[ex] = d*d; }
  __syncthreads();
  if (tid==0){
    float a=0.f;
#pragma unroll
    for (int e=0;e<8;++e) a += dev2[e];
    aux_out[0] = a;
  }
}

// ---------------- gather: slot = padoff[e] + rank; write tok_slot/slot_w/Xg rows ----------------
__global__ __launch_bounds__(256) void gather_kernel(
    const float* __restrict__ x, const int* __restrict__ top_e,
    const float* __restrict__ top_w, const int* __restrict__ tok_rank,
    const int* __restrict__ padoff,
    int* __restrict__ tok_slot, float* __restrict__ slot_w,
    unsigned short* __restrict__ Xg)
{
  const int w = threadIdx.x>>6, lane = threadIdx.x&63;
  const int t = blockIdx.x*4 + w;
  const int s0 = padoff[top_e[2*t]]   + tok_rank[2*t];
  const int s1 = padoff[top_e[2*t+1]] + tok_rank[2*t+1];
  if (lane==0){
    tok_slot[2*t] = s0; tok_slot[2*t+1] = s1;
    slot_w[s0] = top_w[2*t]; slot_w[s1] = top_w[2*t+1];
  }
  us4 o[4];
#pragma unroll
  for (int i=0;i<4;++i){
    const float4 v = *(const float4*)&x[(size_t)t*D_MODEL + i*256 + lane*4];
    o[i][0]=f2bf(v.x); o[i][1]=f2bf(v.y); o[i][2]=f2bf(v.z); o[i][3]=f2bf(v.w);
  }
#pragma unroll
  for (int i=0;i<4;++i) *(us4*)&Xg[(size_t)s0*D_MODEL + i*256 + lane*4] = o[i];
#pragma unroll
  for (int i=0;i<4;++i) *(us4*)&Xg[(size_t)s1*D_MODEL + i*256 + lane*4] = o[i];
}

// ============ grouped GEMM: 128x256, BK=64, 8 waves, 3-buf, 4-phase/K-tile ============
// Per phase: {ds_read group || 2 gl_lds -> barrier -> lgkm0 -> 8 MFMA -> barrier}.
// vmcnt(6) once per K-tile (ph3): loads stay in flight across phases.
// Swizzle: chunk ^= row&7 both-sides (proven 0-conflict). Buffer: A@0(16KB), B@16384(32KB).
template<int KT, int NT, bool G2>
__global__ __launch_bounds__(512,1) void moe_gemm8p(
    const unsigned short* __restrict__ A,
    const unsigned short* __restrict__ Wb,
    const float* __restrict__ bias,
    unsigned short* __restrict__ Cout,
    const int* __restrict__ tileE,
    const int* __restrict__ meta,
    const float* __restrict__ slotw)
{
  constexpr int NX = NT/256;
  constexpr int TOTAL = NX*MAX_TILES;
  constexpr int Q = TOTAL/8, R = TOTAL%8;
  constexpr int NTILES = KT/64;
  constexpr int K3 = (NTILES-4)/3;
  static_assert((NTILES-4)%3 == 0, "tail peel needs (NTILES-4)%3==0");

  const int lid = blockIdx.x;
  const int xcc = lid & 7, jj = lid >> 3;
  const int tsw = xcc*Q + (xcc < R ? xcc : R) + jj;
  const int mtile = tsw / NX, ntile = tsw - mtile*NX;
  if (mtile >= meta[0]) return;

  extern __shared__ char smem[];
  char* const BUF0 = smem;
  char* const BUF1 = smem + 49152;
  char* const BUF2 = smem + 98304;

  const int tid = threadIdx.x;
  const int w = tid>>6, lane = tid&63;
  const int wr = w>>2, wn = w&3;
  const int r15 = lane&15, kg = lane>>4;
  const int e  = tileE[mtile];
  const int m0 = mtile*BMT;
  const int n0 = ntile*256;

  // staging source (pre-swizzled global chunk)
  const int trow = tid>>3;
  const int tch  = ((tid&7) ^ (trow&7))*8;
  const unsigned short* sA = A  + (size_t)(m0 + trow)*KT + tch;
  const unsigned short* sB = Wb + (size_t)e*NT*KT + (size_t)(n0 + trow)*KT + tch;

#define SGA0(BS,KTT) gl_lds16(sA + (size_t)(KTT)*64,                  (BS) + tid*16)
#define SGA1(BS,KTT) gl_lds16(sA + (size_t)(KTT)*64 + (size_t)64*KT,  (BS) + 8192  + tid*16)
#define SGB0(BS,KTT) gl_lds16(sB + (size_t)(KTT)*64,                  (BS) + 16384 + tid*16)
#define SGB1(BS,KTT) gl_lds16(sB + (size_t)(KTT)*64 + (size_t)64*KT,  (BS) + 24576 + tid*16)
#define SGB2(BS,KTT) gl_lds16(sB + (size_t)(KTT)*64 + (size_t)128*KT, (BS) + 32768 + tid*16)
#define SGB3(BS,KTT) gl_lds16(sB + (size_t)(KTT)*64 + (size_t)192*KT, (BS) + 40960 + tid*16)

  const int key4 = (kg ^ (r15&7))<<4;
  const int a0 = (wr*64 + 0*16 + r15)*128 + key4;
  const int a1 = (wr*64 + 1*16 + r15)*128 + key4;
  const int a2 = (wr*64 + 2*16 + r15)*128 + key4;
  const int a3 = (wr*64 + 3*16 + r15)*128 + key4;
  const int b0 = 16384 + (wn*64 + 0*16 + r15)*128 + key4;
  const int b1 = 16384 + (wn*64 + 1*16 + r15)*128 + key4;
  const int b2 = 16384 + (wn*64 + 2*16 + r15)*128 + key4;
  const int b3 = 16384 + (wn*64 + 3*16 + r15)*128 + key4;

  f32x4 acc[4][4];
#pragma unroll
  for (int i=0;i<4;++i)
#pragma unroll
    for (int j=0;j<4;++j) acc[i][j] = (f32x4){0.f,0.f,0.f,0.f};

  short8 AF0, AF1, AF2, AF3, BF0, BF1;

#define MF8(NH) \
    acc[0][2*(NH)]  =__builtin_amdgcn_mfma_f32_16x16x32_bf16(BF0,AF0,acc[0][2*(NH)],0,0,0); \
    acc[0][2*(NH)+1]=__builtin_amdgcn_mfma_f32_16x16x32_bf16(BF1,AF0,acc[0][2*(NH)+1],0,0,0); \
    acc[1][2*(NH)]  =__builtin_amdgcn_mfma_f32_16x16x32_bf16(BF0,AF1,acc[1][2*(NH)],0,0,0); \
    acc[1][2*(NH)+1]=__builtin_amdgcn_mfma_f32_16x16x32_bf16(BF1,AF1,acc[1][2*(NH)+1],0,0,0); \
    acc[2][2*(NH)]  =__builtin_amdgcn_mfma_f32_16x16x32_bf16(BF0,AF2,acc[2][2*(NH)],0,0,0); \
    acc[2][2*(NH)+1]=__builtin_amdgcn_mfma_f32_16x16x32_bf16(BF1,AF2,acc[2][2*(NH)+1],0,0,0); \
    acc[3][2*(NH)]  =__builtin_amdgcn_mfma_f32_16x16x32_bf16(BF0,AF3,acc[3][2*(NH)],0,0,0); \
    acc[3][2*(NH)+1]=__builtin_amdgcn_mfma_f32_16x16x32_bf16(BF1,AF3,acc[3][2*(NH)+1],0,0,0);

#define PH_TAIL(MFS) \
    __builtin_amdgcn_sched_barrier(0); \
    __builtin_amdgcn_s_barrier(); \
    asm volatile("s_waitcnt lgkmcnt(0)" ::: "memory"); \
    __builtin_amdgcn_sched_barrier(0); \
    __builtin_amdgcn_s_setprio(1); \
    MFS \
    __builtin_amdgcn_s_setprio(0); \
    __builtin_amdgcn_sched_barrier(0); \
    __builtin_amdgcn_s_barrier();

// one K-tile = 4 phases. Stage of K-tile KTT into BS (6 loads spread over ph0-2).
// VM_STMT placed in ph3 before the pre-MFMA barrier.
#define TILE8(BC, BS, KTT, DOSTG, VM_STMT) do{ \
    /* ph0: ks0 x B01 */ \
    AF0=*(const short8*)((BC)+a0); AF1=*(const short8*)((BC)+a1); \
    AF2=*(const short8*)((BC)+a2); AF3=*(const short8*)((BC)+a3); \
    BF0=*(const short8*)((BC)+b0); BF1=*(const short8*)((BC)+b1); \
    if (DOSTG){ SGA0(BS,KTT); SGA1(BS,KTT); } \
    PH_TAIL(MF8(0)) \
    /* ph1: ks0 x B23 */ \
    BF0=*(const short8*)((BC)+b2); BF1=*(const short8*)((BC)+b3); \
    if (DOSTG){ SGB0(BS,KTT); SGB1(BS,KTT); } \
    PH_TAIL(MF8(1)) \
    /* ph2: ks1 x B01 */ \
    AF0=*(const short8*)((BC)+(a0^64)); AF1=*(const short8*)((BC)+(a1^64)); \
    AF2=*(const short8*)((BC)+(a2^64)); AF3=*(const short8*)((BC)+(a3^64)); \
    BF0=*(const short8*)((BC)+(b0^64)); BF1=*(const short8*)((BC)+(b1^64)); \
    if (DOSTG){ SGB2(BS,KTT); SGB3(BS,KTT); } \
    PH_TAIL(MF8(0)) \
    /* ph3: ks1 x B23 */ \
    BF0=*(const short8*)((BC)+(b2^64)); BF1=*(const short8*)((BC)+(b3^64)); \
    VM_STMT; \
    PH_TAIL(MF8(1)) \
  }while(0)

  // prologue: stage tiles 0 (buf0) and 1 (buf1); wait tile 0's loads
  SGA0(BUF0,0); SGA1(BUF0,0); SGB0(BUF0,0); SGB1(BUF0,0); SGB2(BUF0,0); SGB3(BUF0,0);
  SGA0(BUF1,1); SGA1(BUF1,1); SGB0(BUF1,1); SGB1(BUF1,1); SGB2(BUF1,1); SGB3(BUF1,1);
  vmw<6>();
  __builtin_amdgcn_s_barrier();

#pragma unroll 1
  for (int i = 0; i < K3; ++i){
    const int kt = i*3;
    TILE8(BUF0, BUF2, kt+2, true, vmw<6>());
    TILE8(BUF1, BUF0, kt+3, true, vmw<6>());
    TILE8(BUF2, BUF1, kt+4, true, vmw<6>());
  }
  TILE8(BUF0, BUF2, NTILES-2, true, vmw<6>());   // tile NTILES-4
  TILE8(BUF1, BUF0, NTILES-1, true, vmw<6>());   // tile NTILES-3
  TILE8(BUF2, BUF0, 0, false, vmw<0>());         // tile NTILES-2: drain last loads
  TILE8(BUF0, BUF0, 0, false, (void)0);          // tile NTILES-1
#undef TILE8
#undef PH_TAIL
#undef MF8
#undef SGA0
#undef SGA1
#undef SGB0
#undef SGB1
#undef SGB2
#undef SGB3

  // epilogue: lane r15 <-> m, kg*4 + reg <-> n  (verified layout)
  const int ng4 = kg*4;
#pragma unroll
  for (int mf=0; mf<4; ++mf){
    const int m = m0 + wr*64 + mf*16 + r15;
    float wg = 0.f;
    if (G2) wg = slotw[m];
#pragma unroll
    for (int nf=0; nf<4; ++nf){
      const int nb = n0 + wn*64 + nf*16 + ng4;
      const float4 bv = *(const float4*)&bias[(size_t)e*NT + nb];
      float q0 = acc[mf][nf][0] + bv.x;
      float q1 = acc[mf][nf][1] + bv.y;
      float q2 = acc[mf][nf][2] + bv.z;
      float q3 = acc[mf][nf][3] + bv.w;
      if (!G2){
        q0=fmaxf(q0,0.f); q1=fmaxf(q1,0.f); q2=fmaxf(q2,0.f); q3=fmaxf(q3,0.f);
      } else {
        q0*=wg; q1*=wg; q2*=wg; q3*=wg;
      }
      us4 o; o[0]=f2bf(q0); o[1]=f2bf(q1); o[2]=f2bf(q2); o[3]=f2bf(q3);
      *(us4*)&Cout[(size_t)m*NT + nb] = o;
    }
  }
}

// ---------------- combine: out[t] = Y[slot0] + Y[slot1] ----------------
__global__ __launch_bounds__(256) void combine_kernel(
    const unsigned short* __restrict__ Yb, const int* __restrict__ tok_slot,
    float* __restrict__ out)
{
  const int t = blockIdx.x;
  const int tid = threadIdx.x;
  const int s0 = tok_slot[2*t], s1 = tok_slot[2*t+1];
  const us4 a = *(const us4*)&Yb[(size_t)s0*D_MODEL + tid*4];
  const us4 b = *(const us4*)&Yb[(size_t)s1*D_MODEL + tid*4];
  float4 o;
  o.x = bf2f(a[0]) + bf2f(b[0]);
  o.y = bf2f(a[1]) + bf2f(b[1]);
  o.z = bf2f(a[2]) + bf2f(b[2]);
  o.w = bf2f(a[3]) + bf2f(b[3]);
  *(float4*)&out[(size_t)t*D_MODEL + tid*4] = o;
}

extern "C" void kernel_launch(void* const* d_in, const int* in_sizes, int n_in,
                              void* d_out, int out_size, void* d_ws, size_t ws_size,
                              hipStream_t stream)
{
  const float* x  = (const float*)d_in[0];
  const float* Wr = (const float*)d_in[1];
  const float* br = (const float*)d_in[2];
  const float* W1 = (const float*)d_in[3];
  const float* b1 = (const float*)d_in[4];
  const float* W2 = (const float*)d_in[5];
  const float* b2 = (const float*)d_in[6];
  float* out = (float*)d_out;
  char* ws = (char*)d_ws;

  const bool bigws = ws_size >= REQ_BIG;

  int*   cursors = (int*)(ws + WS_CURSORS);
  int*   padoff  = (int*)(ws + WS_PADOFF);
  int*   meta    = (int*)(ws + WS_META);
  int*   tileE   = (int*)(ws + WS_TILE_E);
  float* pp      = (float*)(ws + WS_PP);
  int*   top_e   = (int*)(ws + WS_TOP_E);
  float* top_w   = (float*)(ws + WS_TOP_W);
  int*   tok_rank= (int*)(ws + WS_TOK_RANK);
  float* slot_w  = (float*)(ws + WS_SLOT_W);
  int*   tok_slot= (int*)(ws + WS_TOK_SLOT);
  unsigned short* Xg  = (unsigned short*)(ws + WS_XG);
  unsigned short* Hb  = (unsigned short*)(ws + WS_HB);
  unsigned short* Wb  = (unsigned short*)(ws + WS_WB);
  unsigned short* W2b = (unsigned short*)(ws + WS_WB2);
  unsigned short* Yb  = Xg;   // Xg dead after GEMM1

  hipFuncSetAttribute((const void*)moe_gemm8p<D_MODEL, EXP_D, false>,
                      hipFuncAttributeMaxDynamicSharedMemorySize, 147456);
  hipFuncSetAttribute((const void*)moe_gemm8p<EXP_D, D_MODEL, true>,
                      hipFuncAttributeMaxDynamicSharedMemorySize, 147456);

  const int n4 = NE*EXP_D*D_MODEL/4;
  hipMemsetAsync(ws, 0, 128, stream);   // counts/cursors zero
  if (bigws){
    router_cvt_kernel<<<dim3(NTOK/4 + 4096), dim3(256), 0, stream>>>(
        x, Wr, br, top_e, top_w, pp, W1, Wb, W2, W2b, 2*n4);
  } else {
    router_cvt_kernel<<<dim3(NTOK/4 + 2048), dim3(256), 0, stream>>>(
        x, Wr, br, top_e, top_w, pp, W1, Wb, W2, Wb, n4);
  }
  scatter_kernel<<<dim3(NTOK/1024), dim3(1024), 0, stream>>>(top_e, cursors, tok_rank);
  prefix_kernel<<<dim3(1), dim3(256), 0, stream>>>((int*)ws, pp, out + (size_t)NTOK*D_MODEL);
  gather_kernel<<<dim3(NTOK/4), dim3(256), 0, stream>>>(x, top_e, top_w, tok_rank, padoff,
                                                        tok_slot, slot_w, Xg);
  moe_gemm8p<D_MODEL, EXP_D, false>
      <<<dim3((EXP_D/256)*MAX_TILES), dim3(512), 147456, stream>>>(
      Xg, Wb, b1, Hb, tileE, meta, slot_w);
  if (!bigws){
    cvt_kernel<<<dim3(2048), dim3(256), 0, stream>>>(W2, Wb);
  }
  moe_gemm8p<EXP_D, D_MODEL, true>
      <<<dim3((D_MODEL/256)*MAX_TILES), dim3(512), 147456, stream>>>(
      Hb, bigws ? W2b : Wb, b2, Yb, tileE, meta, slot_w);
  combine_kernel<<<dim3(NTOK), dim3(256), 0, stream>>>(Yb, tok_slot, out);
}

// Round 11
// 500.267 us; speedup vs baseline: 1.0585x; 1.0585x over previous
//
#include <hip/hip_runtime.h>
#include <stdint.h>

#define D_MODEL 1024
#define EXP_D   4096
#define NE      8
#define NTOK    8192
#define BMT     128
#define MAX_TILES 136
#define MAXT256 72
#define MAXT128H 144

typedef __attribute__((ext_vector_type(8))) short short8;
typedef __attribute__((ext_vector_type(4))) float f32x4;
typedef __attribute__((ext_vector_type(4))) unsigned short us4;

// ---- workspace layout (bytes) ----
#define WS_CURSORS   32         // int[8]
#define WS_PADOFF    64         // int[16]
#define WS_META      128        // int[32], meta[0]=nt (GEMM1 tiles), meta[1]=2*nt
#define WS_TILE_E    256        // int[960]
#define WS_PP        4096       // float[2048*8]
#define WS_TOP_E     69632      // int[16384]
#define WS_TOP_W     135168     // float[16384]
#define WS_TOK_RANK  200704     // int[16384]
#define WS_SLOT_W    270336     // float[18432]
#define WS_TOK_SLOT  344064     // int[16384]
#define WS_XG        409600     // bf16 rows x 1024 (Yb aliases this)
// old (128-pad) layout:
#define WS_HB_OLD    36057088   // needs XG rows 17408 -> XG fits [409600, 36057088)? 17408*2048=35651584 ->ends 36061184 >36057088! shift:
// -> use XG at 409600 ends 36,061,184 ; HB_OLD at 36061184 ends 178667520 ; WB_OLD at 178667520 ends 245776384
#define WS_HB_O      36061184
#define WS_WB_O      178667520
#define REQ_OLD      245776384ull
// new (256-pad) layout: XG 18432 rows ends 38158336 ; HB ends 189153280 ; WB ends 256262144
#define WS_HB_N      38158336
#define WS_WB_N      189153280
#define REQ_NEW      256262144ull

__device__ __forceinline__ unsigned short f2bf(float f){
  __bf16 h = (__bf16)f;
  return __builtin_bit_cast(unsigned short, h);
}
__device__ __forceinline__ float bf2f(unsigned short u){
  unsigned int v = ((unsigned int)u) << 16;
  return __builtin_bit_cast(float, v);
}
__device__ __forceinline__ void gl_lds16(const void* g, void* l){
  __builtin_amdgcn_global_load_lds((const __attribute__((address_space(1))) unsigned int*)g,
                                   (__attribute__((address_space(3))) unsigned int*)l,
                                   16, 0, 0);
}

template<int N> __device__ __forceinline__ void vmw(){
  if constexpr (N==0)      asm volatile("s_waitcnt vmcnt(0)" ::: "memory");
  else if constexpr (N==2) asm volatile("s_waitcnt vmcnt(2)" ::: "memory");
  else if constexpr (N==4) asm volatile("s_waitcnt vmcnt(4)" ::: "memory");
  else if constexpr (N==6) asm volatile("s_waitcnt vmcnt(6)" ::: "memory");
}

// ---------------- router (blocks 0..2047, NO atomics) + W1 cvt (blocks >=2048) ----------------
__global__ __launch_bounds__(256) void router_cvt_kernel(
    const float* __restrict__ x, const float* __restrict__ Wr,
    const float* __restrict__ br,
    int* __restrict__ top_e, float* __restrict__ top_w,
    float* __restrict__ pp,
    const float* __restrict__ W1, unsigned short* __restrict__ Wb)
{
  const int tid = threadIdx.x;
  if ((int)blockIdx.x >= NTOK/4){
    const int n4 = NE*EXP_D*D_MODEL/4;
    for (int i = ((int)blockIdx.x - NTOK/4)*256 + tid; i < n4; i += 2048*256){
      const float4 v = *(const float4*)&W1[(size_t)i*4];
      us4 o; o[0]=f2bf(v.x); o[1]=f2bf(v.y); o[2]=f2bf(v.z); o[3]=f2bf(v.w);
      *(us4*)&Wb[(size_t)i*4] = o;
    }
    return;
  }
  __shared__ float WrS[NE*D_MODEL];
  __shared__ float wprob[4][NE];
#pragma unroll
  for (int i=0;i<8;++i){
    int j = (tid + i*256)*4;
    *(float4*)&WrS[j] = *(const float4*)&Wr[j];
  }
  __syncthreads();
  const int w = tid>>6, lane = tid&63;
  const int t = blockIdx.x*4 + w;
  const float* xt = x + (size_t)t*D_MODEL;
  float accv[8] = {0,0,0,0,0,0,0,0};
#pragma unroll
  for (int i=0;i<4;++i){
    const int k = i*256 + lane*4;
    const float4 xv = *(const float4*)&xt[k];
#pragma unroll
    for (int e=0;e<8;++e){
      const float4 wv = *(const float4*)&WrS[e*D_MODEL + k];
      accv[e] += xv.x*wv.x + xv.y*wv.y + xv.z*wv.z + xv.w*wv.w;
    }
  }
#pragma unroll
  for (int m=32;m>0;m>>=1){
#pragma unroll
    for (int e=0;e<8;++e) accv[e] += __shfl_xor(accv[e], m, 64);
  }
  if (lane==0){
    float lg[8];
#pragma unroll
    for (int e=0;e<8;++e) lg[e] = accv[e] + br[e];
    float mx = lg[0];
#pragma unroll
    for (int e=1;e<8;++e) mx = fmaxf(mx, lg[e]);
    float p[8]; float s=0.f;
#pragma unroll
    for (int e=0;e<8;++e){ p[e] = __expf(lg[e]-mx); s += p[e]; }
    const float inv = 1.f/s;
#pragma unroll
    for (int e=0;e<8;++e){ p[e] *= inv; wprob[w][e] = p[e]; }
    int i1=0; float p1v=p[0];
#pragma unroll
    for (int e=1;e<8;++e) if (p[e] > p1v){ p1v=p[e]; i1=e; }
    int i2=-1; float p2v=-1.f;
#pragma unroll
    for (int e=0;e<8;++e) if (e!=i1 && p[e] > p2v){ p2v=p[e]; i2=e; }
    const float rn = 1.f/(p1v+p2v);
    top_e[2*t]   = i1; top_w[2*t]   = p1v*rn;
    top_e[2*t+1] = i2; top_w[2*t+1] = p2v*rn;
  }
  __syncthreads();
  if (tid<8){
    pp[blockIdx.x*8+tid] = wprob[0][tid]+wprob[1][tid]+wprob[2][tid]+wprob[3][tid];
  }
}

// ---------------- standalone cvt (W2) ----------------
__global__ __launch_bounds__(256) void cvt_kernel(const float* __restrict__ W,
                                                  unsigned short* __restrict__ Wb){
  const int n4 = NE*EXP_D*D_MODEL/4;
  for (int i = blockIdx.x*256 + threadIdx.x; i < n4; i += gridDim.x*256){
    const float4 v = *(const float4*)&W[(size_t)i*4];
    us4 o; o[0]=f2bf(v.x); o[1]=f2bf(v.y); o[2]=f2bf(v.z); o[3]=f2bf(v.w);
    *(us4*)&Wb[(size_t)i*4] = o;
  }
}

// ---------------- scatter: LDS-aggregated counting + expert-local ranks ----------------
__global__ __launch_bounds__(1024) void scatter_kernel(
    const int* __restrict__ top_e,
    int* __restrict__ cursors, int* __restrict__ tok_rank)
{
  __shared__ int cnt[NE];
  __shared__ int base[NE];
  const int tid = threadIdx.x;
  if (tid < NE) cnt[tid] = 0;
  __syncthreads();
  const int t = blockIdx.x*1024 + tid;
  const int e0 = top_e[2*t], e1 = top_e[2*t+1];
  const int p0 = atomicAdd(&cnt[e0], 1);
  const int p1 = atomicAdd(&cnt[e1], 1);
  __syncthreads();
  if (tid < NE) base[tid] = atomicAdd(&cursors[tid], cnt[tid]);
  __syncthreads();
  tok_rank[2*t]   = base[e0] + p0;
  tok_rank[2*t+1] = base[e1] + p1;
}

// ---------------- prefix (AFTER scatter): tile table + aux; align = 1<<shift ----------------
__global__ __launch_bounds__(256) void prefix_kernel(int* __restrict__ wsI,
                                                     const float* __restrict__ pp,
                                                     float* __restrict__ aux_out,
                                                     int shift){
  const int tid = threadIdx.x;
  int* counts = wsI + 8;
  int* padoff = wsI + 16;
  int* meta   = wsI + 32;
  int* tileE  = wsI + 64;
  __shared__ int tileCum[9];
  __shared__ float dev2[8];
  if (tid==0){
    int nt = 0;
    tileCum[0] = 0;
    const int am1 = (1<<shift) - 1;
    for (int e=0;e<NE;++e){
      padoff[e] = nt << shift;
      nt += (counts[e] + am1) >> shift;
      tileCum[e+1] = nt;
    }
    meta[0] = nt;
    meta[1] = 2*nt;
  }
  __syncthreads();
  const int nt = tileCum[8];
  for (int i=tid; i<nt; i+=256){
    int e = 0;
    while (tileCum[e+1] <= i) ++e;
    tileE[i] = e;
  }
  const int ex = tid>>5, j = tid&31;
  float s = 0.f;
  for (int b=j; b<NTOK/4; b+=32) s += pp[b*8+ex];
#pragma unroll
  for (int m=16;m>0;m>>=1) s += __shfl_xor(s, m, 64);
  if (j==0){ float d = s*(1.f/(float)NTOK) - 0.125f; dev2[ex] = d*d; }
  __syncthreads();
  if (tid==0){
    float a=0.f;
#pragma unroll
    for (int e=0;e<8;++e) a += dev2[e];
    aux_out[0] = a;
  }
}

// ---------------- gather: slot = padoff[e] + rank; write tok_slot/slot_w/Xg rows ----------------
__global__ __launch_bounds__(256) void gather_kernel(
    const float* __restrict__ x, const int* __restrict__ top_e,
    const float* __restrict__ top_w, const int* __restrict__ tok_rank,
    const int* __restrict__ padoff,
    int* __restrict__ tok_slot, float* __restrict__ slot_w,
    unsigned short* __restrict__ Xg)
{
  const int w = threadIdx.x>>6, lane = threadIdx.x&63;
  const int t = blockIdx.x*4 + w;
  const int s0 = padoff[top_e[2*t]]   + tok_rank[2*t];
  const int s1 = padoff[top_e[2*t+1]] + tok_rank[2*t+1];
  if (lane==0){
    tok_slot[2*t] = s0; tok_slot[2*t+1] = s1;
    slot_w[s0] = top_w[2*t]; slot_w[s1] = top_w[2*t+1];
  }
  us4 o[4];
#pragma unroll
  for (int i=0;i<4;++i){
    const float4 v = *(const float4*)&x[(size_t)t*D_MODEL + i*256 + lane*4];
    o[i][0]=f2bf(v.x); o[i][1]=f2bf(v.y); o[i][2]=f2bf(v.z); o[i][3]=f2bf(v.w);
  }
#pragma unroll
  for (int i=0;i<4;++i) *(us4*)&Xg[(size_t)s0*D_MODEL + i*256 + lane*4] = o[i];
#pragma unroll
  for (int i=0;i<4;++i) *(us4*)&Xg[(size_t)s1*D_MODEL + i*256 + lane*4] = o[i];
}

// ============ NEW GEMM1: 256x256 tile, BK=64, 8 waves (128x64/wave), 2-buf, 4 fine phases ============
// Phase: {ds_reads || 2 gl_lds -> barrier -> lgkm0 -> 16 MFMA -> barrier}.
// Stage order per K-tile: B01,B23,A02,A13 -> counted waits vmcnt(4)@ph1, vmcnt(2)@ph3 (never 0).
template<int KT, int NT>
__global__ __launch_bounds__(512,1) void moe_g256(
    const unsigned short* __restrict__ A,
    const unsigned short* __restrict__ Wb,
    const float* __restrict__ bias,
    unsigned short* __restrict__ Cout,
    const int* __restrict__ tileE,
    const int* __restrict__ meta)
{
  constexpr int NX = NT/256;
  constexpr int TOTAL = NX*MAXT256;
  constexpr int Q = TOTAL/8, R = TOTAL%8;
  constexpr int NTILES = KT/64;
  static_assert(NTILES%2==0 && NTILES>=4, "even K-tiles");

  const int lid = blockIdx.x;
  const int xcc = lid & 7, jj = lid >> 3;
  const int tsw = xcc*Q + (xcc < R ? xcc : R) + jj;
  const int mtile = tsw / NX, ntile = tsw - mtile*NX;
  if (mtile >= meta[0]) return;

  extern __shared__ char smem[];
  char* const BUF0 = smem;
  char* const BUF1 = smem + 65536;

  const int tid = threadIdx.x;
  const int w = tid>>6, lane = tid&63;
  const int wr = w>>2, wn = w&3;
  const int r15 = lane&15, kg = lane>>4;
  const int e  = tileE[mtile];
  const int m0 = mtile*256;
  const int n0 = ntile*256;

  // staging source (pre-swizzled global chunk); dest linear tid*16 per 64-row block
  const int trow = tid>>3;                  // 0..63
  const int tch  = ((tid&7) ^ (trow&7))*8;
  const unsigned short* sA = A  + (size_t)(m0 + trow)*KT + tch;
  const unsigned short* sB = Wb + (size_t)e*NT*KT + (size_t)(n0 + trow)*KT + tch;

#define SG_B01(BS,KTT) do{ \
  gl_lds16(sB + (size_t)(KTT)*64,                  (BS)+32768+tid*16); \
  gl_lds16(sB + (size_t)(KTT)*64 + (size_t)64*KT,  (BS)+40960+tid*16); }while(0)
#define SG_B23(BS,KTT) do{ \
  gl_lds16(sB + (size_t)(KTT)*64 + (size_t)128*KT, (BS)+49152+tid*16); \
  gl_lds16(sB + (size_t)(KTT)*64 + (size_t)192*KT, (BS)+57344+tid*16); }while(0)
#define SG_A02(BS,KTT) do{ \
  gl_lds16(sA + (size_t)(KTT)*64,                  (BS)+tid*16); \
  gl_lds16(sA + (size_t)(KTT)*64 + (size_t)128*KT, (BS)+16384+tid*16); }while(0)
#define SG_A13(BS,KTT) do{ \
  gl_lds16(sA + (size_t)(KTT)*64 + (size_t)64*KT,  (BS)+8192+tid*16); \
  gl_lds16(sA + (size_t)(KTT)*64 + (size_t)192*KT, (BS)+24576+tid*16); }while(0)

  const int key4 = (kg ^ (r15&7))<<4;
  const int aw = (wr*128 + r15)*128 + key4;          // + qb*128 + mi*2048  (A base 0)
  const int bw = 32768 + (wn*64 + r15)*128 + key4;   // + nf*2048

  f32x4 acc[8][4];
#pragma unroll
  for (int i=0;i<8;++i)
#pragma unroll
    for (int j=0;j<4;++j) acc[i][j] = (f32x4){0.f,0.f,0.f,0.f};

  short8 Aq[8], Bq[4];

#define RD_A(BC, QB) do{ _Pragma("unroll") for(int mi=0;mi<4;++mi){ \
    const int off_ = aw + (QB)*128 + mi*2048; \
    Aq[mi*2]   = *(const short8*)((BC)+off_); \
    Aq[mi*2+1] = *(const short8*)((BC)+(off_^64)); }}while(0)
#define RD_B(BC, NF0) do{ _Pragma("unroll") for(int nf=0;nf<2;++nf){ \
    const int off_ = bw + ((NF0)+nf)*2048; \
    Bq[nf*2]   = *(const short8*)((BC)+off_); \
    Bq[nf*2+1] = *(const short8*)((BC)+(off_^64)); }}while(0)

#define MFQ(MB, NF0) \
  _Pragma("unroll") for(int mi=0;mi<4;++mi) \
  _Pragma("unroll") for(int nf=0;nf<2;++nf){ \
    acc[(MB)+mi][(NF0)+nf]=__builtin_amdgcn_mfma_f32_16x16x32_bf16(Bq[nf*2],Aq[mi*2],acc[(MB)+mi][(NF0)+nf],0,0,0); \
    acc[(MB)+mi][(NF0)+nf]=__builtin_amdgcn_mfma_f32_16x16x32_bf16(Bq[nf*2+1],Aq[mi*2+1],acc[(MB)+mi][(NF0)+nf],0,0,0); }

#define PH_TAIL(MFS) \
    __builtin_amdgcn_sched_barrier(0); \
    __builtin_amdgcn_s_barrier(); \
    asm volatile("s_waitcnt lgkmcnt(0)" ::: "memory"); \
    __builtin_amdgcn_sched_barrier(0); \
    __builtin_amdgcn_s_setprio(1); \
    MFS \
    __builtin_amdgcn_s_setprio(0); \
    __builtin_amdgcn_sched_barrier(0); \
    __builtin_amdgcn_s_barrier();

#define T256(BC,BS,KTN,DOSTG,VM1,VM3) do{ \
    RD_A(BC,0); RD_B(BC,0); if(DOSTG){ SG_B01(BS,KTN); } \
    PH_TAIL(MFQ(0,0)) \
    RD_B(BC,2); if(DOSTG){ SG_B23(BS,KTN); } \
    VM1; \
    PH_TAIL(MFQ(0,2)) \
    RD_A(BC,64); RD_B(BC,0); if(DOSTG){ SG_A02(BS,KTN); } \
    PH_TAIL(MFQ(4,0)) \
    RD_B(BC,2); if(DOSTG){ SG_A13(BS,KTN); } \
    VM3; \
    PH_TAIL(MFQ(4,2)) \
  }while(0)

  // prologue: stage K-tile 0 into BUF0; wait until only A13(0) in flight
  SG_B01(BUF0,0); SG_B23(BUF0,0); SG_A02(BUF0,0); SG_A13(BUF0,0);
  vmw<2>();
  __builtin_amdgcn_s_barrier();

#pragma unroll 1
  for (int i = 0; i < (NTILES-2)/2; ++i){
    T256(BUF0, BUF1, 2*i+1, true, vmw<4>(), vmw<2>());
    T256(BUF1, BUF0, 2*i+2, true, vmw<4>(), vmw<2>());
  }
  T256(BUF0, BUF1, NTILES-1, true, vmw<4>(), vmw<2>());  // tile NTILES-2
  T256(BUF1, BUF0, 0, false, vmw<0>(), (void)0);         // tile NTILES-1
#undef T256
#undef PH_TAIL
#undef MFQ
#undef RD_A
#undef RD_B
#undef SG_B01
#undef SG_B23
#undef SG_A02
#undef SG_A13

  // epilogue (GEMM1: +bias, relu): m = m0 + wr*128 + mi*16 + r15; n = n0 + wn*64 + nf*16 + kg*4
  const int ng4 = kg*4;
#pragma unroll
  for (int mi=0; mi<8; ++mi){
    const int m = m0 + wr*128 + mi*16 + r15;
#pragma unroll
    for (int nf=0; nf<4; ++nf){
      const int nb = n0 + wn*64 + nf*16 + ng4;
      const float4 bv = *(const float4*)&bias[(size_t)e*NT + nb];
      float q0 = fmaxf(acc[mi][nf][0] + bv.x, 0.f);
      float q1 = fmaxf(acc[mi][nf][1] + bv.y, 0.f);
      float q2 = fmaxf(acc[mi][nf][2] + bv.z, 0.f);
      float q3 = fmaxf(acc[mi][nf][3] + bv.w, 0.f);
      us4 o; o[0]=f2bf(q0); o[1]=f2bf(q1); o[2]=f2bf(q2); o[3]=f2bf(q3);
      *(us4*)&Cout[(size_t)m*NT + nb] = o;
    }
  }
}

// ============ FALLBACK GEMM1: 128x512 tile, BK=64, 8 waves (128x64/wave), 2-buf (round-9) ============
template<int KT, int NT>
__global__ __launch_bounds__(512,1) void moe_gemm_w(
    const unsigned short* __restrict__ A,
    const unsigned short* __restrict__ Wb,
    const float* __restrict__ bias,
    unsigned short* __restrict__ Cout,
    const int* __restrict__ tileE,
    const int* __restrict__ meta)
{
  constexpr int NX = NT/512;
  constexpr int TOTAL = NX*MAX_TILES;
  constexpr int Q = TOTAL/8, R = TOTAL%8;
  constexpr int NTILES = KT/64;

  const int lid = blockIdx.x;
  const int xcc = lid & 7, jj = lid >> 3;
  const int tsw = xcc*Q + (xcc < R ? xcc : R) + jj;
  const int mtile = tsw / NX, ntile = tsw - mtile*NX;
  if (mtile >= meta[0]) return;

  extern __shared__ char smem[];
  char* const BUF0 = smem;
  char* const BUF1 = smem + 81920;

  const int tid = threadIdx.x;
  const int w = tid>>6, lane = tid&63;
  const int r15 = lane&15, kg = lane>>4;
  const int e  = tileE[mtile];
  const int m0 = mtile*BMT;
  const int n0 = ntile*512;

  const int trow = tid>>3;
  const int tch  = ((tid&7) ^ (trow&7))*8;
  const unsigned short* sA = A  + (size_t)(m0 + trow)*KT + tch;
  const unsigned short* sB = Wb + (size_t)e*NT*KT + (size_t)(n0 + trow)*KT + tch;

#define WSTG(BS, KTT) do{ \
    gl_lds16(sA + (size_t)(KTT)*64,                  (BS) + tid*16); \
    gl_lds16(sA + (size_t)(KTT)*64 + (size_t)64*KT,  (BS) + 8192 + tid*16); \
    _Pragma("unroll") \
    for (int jq=0;jq<8;++jq) \
      gl_lds16(sB + (size_t)(KTT)*64 + (size_t)(64*jq)*KT, (BS) + 16384 + jq*8192 + tid*16); \
  }while(0)

  const int key4  = (kg ^ (r15&7))<<4;
  const int abase = r15*128 + key4;
  const int bbase = 16384 + w*8192 + r15*128 + key4;

  f32x4 acc[8][4];
#pragma unroll
  for (int i=0;i<8;++i)
#pragma unroll
    for (int j=0;j<4;++j) acc[i][j] = (f32x4){0.f,0.f,0.f,0.f};

  short8 A0[8], A1[8], B0[4], B1[4];

#define RD0(BB) do{ const char* pa=(BB)+abase; const char* pb=(BB)+bbase; \
  _Pragma("unroll") for(int q=0;q<8;++q) A0[q]=*(const short8*)(pa+q*2048); \
  _Pragma("unroll") for(int q=0;q<4;++q) B0[q]=*(const short8*)(pb+q*2048); }while(0)
#define RD1(BB) do{ const char* pa=(BB)+(abase^64); const char* pb=(BB)+(bbase^64); \
  _Pragma("unroll") for(int q=0;q<8;++q) A1[q]=*(const short8*)(pa+q*2048); \
  _Pragma("unroll") for(int q=0;q<4;++q) B1[q]=*(const short8*)(pb+q*2048); }while(0)

#define MM32(AX,BX) do{ \
  _Pragma("unroll") for(int mi=0;mi<8;++mi) \
  _Pragma("unroll") for(int nf=0;nf<4;++nf) \
    acc[mi][nf]=__builtin_amdgcn_mfma_f32_16x16x32_bf16(BX[nf],AX[mi],acc[mi][nf],0,0,0); \
}while(0)

#define WTILE(BC,BN1,STG_STMT) do{ \
  RD1(BC); \
  STG_STMT; \
  __builtin_amdgcn_sched_barrier(0); \
  __builtin_amdgcn_s_setprio(1); MM32(A0,B0); __builtin_amdgcn_s_setprio(0); \
  __builtin_amdgcn_sched_barrier(0); \
  asm volatile("s_waitcnt vmcnt(0)" ::: "memory"); \
  asm volatile("s_waitcnt lgkmcnt(0)" ::: "memory"); \
  __builtin_amdgcn_sched_barrier(0); \
  __builtin_amdgcn_s_barrier(); \
  RD0(BN1); \
  __builtin_amdgcn_sched_barrier(0); \
  __builtin_amdgcn_s_setprio(1); MM32(A1,B1); __builtin_amdgcn_s_setprio(0); \
  __builtin_amdgcn_sched_barrier(0); \
}while(0)

  WSTG(BUF0, 0);
  asm volatile("s_waitcnt vmcnt(0)" ::: "memory");
  __builtin_amdgcn_s_barrier();
  RD0(BUF0);

#pragma unroll 1
  for (int i = 0; i < (NTILES-2)/2; ++i){
    WTILE(BUF0, BUF1, WSTG(BUF1, 2*i+1));
    WTILE(BUF1, BUF0, WSTG(BUF0, 2*i+2));
  }
  WTILE(BUF0, BUF1, WSTG(BUF1, NTILES-1));
  {
    RD1(BUF1);
    __builtin_amdgcn_sched_barrier(0);
    __builtin_amdgcn_s_setprio(1); MM32(A0,B0); __builtin_amdgcn_s_setprio(0);
    asm volatile("s_waitcnt lgkmcnt(0)" ::: "memory");
    __builtin_amdgcn_sched_barrier(0);
    __builtin_amdgcn_s_setprio(1); MM32(A1,B1); __builtin_amdgcn_s_setprio(0);
  }
#undef WTILE
#undef MM32
#undef RD0
#undef RD1
#undef WSTG

  const int ng4 = kg*4;
#pragma unroll
  for (int mi=0; mi<8; ++mi){
    const int m = m0 + mi*16 + r15;
#pragma unroll
    for (int nf=0; nf<4; ++nf){
      const int nb = n0 + w*64 + nf*16 + ng4;
      const float4 bv = *(const float4*)&bias[(size_t)e*NT + nb];
      float q0 = fmaxf(acc[mi][nf][0] + bv.x, 0.f);
      float q1 = fmaxf(acc[mi][nf][1] + bv.y, 0.f);
      float q2 = fmaxf(acc[mi][nf][2] + bv.z, 0.f);
      float q3 = fmaxf(acc[mi][nf][3] + bv.w, 0.f);
      us4 o; o[0]=f2bf(q0); o[1]=f2bf(q1); o[2]=f2bf(q2); o[3]=f2bf(q3);
      *(us4*)&Cout[(size_t)m*NT + nb] = o;
    }
  }
}

// ============ GEMM2: 128x256, BK=64, 8 waves, 3-buf pipeline (round-7/9 proven) ============
template<int KT, int NT, int MAXT, bool HALF>
__global__ __launch_bounds__(512,1) void moe_gemm3(
    const unsigned short* __restrict__ A,
    const unsigned short* __restrict__ Wb,
    const float* __restrict__ bias,
    unsigned short* __restrict__ Cout,
    const int* __restrict__ tileE,
    const int* __restrict__ meta,
    const float* __restrict__ slotw)
{
  constexpr int NX = NT/256;
  constexpr int TOTAL = NX*MAXT;
  constexpr int Q = TOTAL/8, R = TOTAL%8;
  constexpr int NTILES = KT/64;
  constexpr int K3 = (NTILES-4)/3;
  static_assert((NTILES-4)%3 == 0, "tail peel needs (NTILES-4)%3==0");

  const int lid = blockIdx.x;
  const int xcc = lid & 7, jj = lid >> 3;
  const int tsw = xcc*Q + (xcc < R ? xcc : R) + jj;
  const int mtile = tsw / NX, ntile = tsw - mtile*NX;
  if (mtile >= meta[HALF ? 1 : 0]) return;

  extern __shared__ char smem[];
  char* const BUF0 = smem;
  char* const BUF1 = smem + 49152;
  char* const BUF2 = smem + 98304;

  const int tid = threadIdx.x;
  const int w = tid>>6, lane = tid&63;
  const int wr = w>>2, wn = w&3;
  const int r15 = lane&15, kg = lane>>4;
  const int e  = tileE[HALF ? (mtile>>1) : mtile];
  const int m0 = mtile*BMT;
  const int n0 = ntile*256;

  const int trow = tid>>3;
  const int tch  = ((tid&7) ^ (trow&7))*8;
  const unsigned short* sA = A  + (size_t)(m0 + trow)*KT + tch;
  const unsigned short* sB = Wb + (size_t)e*NT*KT + (size_t)(n0 + trow)*KT + tch;

#define STG_ALL(BS, KTT) do{ \
    gl_lds16(sA + (size_t)(KTT)*64,                  (BS) + tid*16); \
    gl_lds16(sA + (size_t)(KTT)*64 + (size_t)64*KT,  (BS) + 8192  + tid*16); \
    gl_lds16(sB + (size_t)(KTT)*64,                  (BS) + 16384 + tid*16); \
    gl_lds16(sB + (size_t)(KTT)*64 + (size_t)64*KT,  (BS) + 24576 + tid*16); \
    gl_lds16(sB + (size_t)(KTT)*64 + (size_t)128*KT, (BS) + 32768 + tid*16); \
    gl_lds16(sB + (size_t)(KTT)*64 + (size_t)192*KT, (BS) + 40960 + tid*16); \
  }while(0)

  const int key4 = (kg ^ (r15&7))<<4;
  const int a0 = (wr*64 + 0*16 + r15)*128 + key4;
  const int a1 = (wr*64 + 1*16 + r15)*128 + key4;
  const int a2 = (wr*64 + 2*16 + r15)*128 + key4;
  const int a3 = (wr*64 + 3*16 + r15)*128 + key4;
  const int b0 = 16384 + (wn*64 + 0*16 + r15)*128 + key4;
  const int b1 = 16384 + (wn*64 + 1*16 + r15)*128 + key4;
  const int b2 = 16384 + (wn*64 + 2*16 + r15)*128 + key4;
  const int b3 = 16384 + (wn*64 + 3*16 + r15)*128 + key4;

  f32x4 acc[4][4];
#pragma unroll
  for (int i=0;i<4;++i)
#pragma unroll
    for (int j=0;j<4;++j) acc[i][j] = (f32x4){0.f,0.f,0.f,0.f};

  short8 A0[4], B0[4], A1[4], B1[4];

#define MFMA16(AX, BX) \
    acc[0][0]=__builtin_amdgcn_mfma_f32_16x16x32_bf16(BX[0],AX[0],acc[0][0],0,0,0); \
    acc[0][1]=__builtin_amdgcn_mfma_f32_16x16x32_bf16(BX[1],AX[0],acc[0][1],0,0,0); \
    acc[0][2]=__builtin_amdgcn_mfma_f32_16x16x32_bf16(BX[2],AX[0],acc[0][2],0,0,0); \
    acc[0][3]=__builtin_amdgcn_mfma_f32_16x16x32_bf16(BX[3],AX[0],acc[0][3],0,0,0); \
    acc[1][0]=__builtin_amdgcn_mfma_f32_16x16x32_bf16(BX[0],AX[1],acc[1][0],0,0,0); \
    acc[1][1]=__builtin_amdgcn_mfma_f32_16x16x32_bf16(BX[1],AX[1],acc[1][1],0,0,0); \
    acc[1][2]=__builtin_amdgcn_mfma_f32_16x16x32_bf16(BX[2],AX[1],acc[1][2],0,0,0); \
    acc[1][3]=__builtin_amdgcn_mfma_f32_16x16x32_bf16(BX[3],AX[1],acc[1][3],0,0,0); \
    acc[2][0]=__builtin_amdgcn_mfma_f32_16x16x32_bf16(BX[0],AX[2],acc[2][0],0,0,0); \
    acc[2][1]=__builtin_amdgcn_mfma_f32_16x16x32_bf16(BX[1],AX[2],acc[2][1],0,0,0); \
    acc[2][2]=__builtin_amdgcn_mfma_f32_16x16x32_bf16(BX[2],AX[2],acc[2][2],0,0,0); \
    acc[2][3]=__builtin_amdgcn_mfma_f32_16x16x32_bf16(BX[3],AX[2],acc[2][3],0,0,0); \
    acc[3][0]=__builtin_amdgcn_mfma_f32_16x16x32_bf16(BX[0],AX[3],acc[3][0],0,0,0); \
    acc[3][1]=__builtin_amdgcn_mfma_f32_16x16x32_bf16(BX[1],AX[3],acc[3][1],0,0,0); \
    acc[3][2]=__builtin_amdgcn_mfma_f32_16x16x32_bf16(BX[2],AX[3],acc[3][2],0,0,0); \
    acc[3][3]=__builtin_amdgcn_mfma_f32_16x16x32_bf16(BX[3],AX[3],acc[3][3],0,0,0);

#define RD_KS1(BC) do{ \
    A1[0] = *(const short8*)((BC) + (a0 ^ 64)); \
    A1[1] = *(const short8*)((BC) + (a1 ^ 64)); \
    A1[2] = *(const short8*)((BC) + (a2 ^ 64)); \
    A1[3] = *(const short8*)((BC) + (a3 ^ 64)); \
    B1[0] = *(const short8*)((BC) + (b0 ^ 64)); \
    B1[1] = *(const short8*)((BC) + (b1 ^ 64)); \
    B1[2] = *(const short8*)((BC) + (b2 ^ 64)); \
    B1[3] = *(const short8*)((BC) + (b3 ^ 64)); \
  }while(0)
#define RD_KS0(BN1) do{ \
    A0[0] = *(const short8*)((BN1) + a0); \
    A0[1] = *(const short8*)((BN1) + a1); \
    A0[2] = *(const short8*)((BN1) + a2); \
    A0[3] = *(const short8*)((BN1) + a3); \
    B0[0] = *(const short8*)((BN1) + b0); \
    B0[1] = *(const short8*)((BN1) + b1); \
    B0[2] = *(const short8*)((BN1) + b2); \
    B0[3] = *(const short8*)((BN1) + b3); \
  }while(0)

#define TILE(BC, BN1, STG_STMT, VM_STMT) do{ \
    RD_KS1(BC); \
    STG_STMT; \
    __builtin_amdgcn_sched_barrier(0); \
    __builtin_amdgcn_s_setprio(1); \
    MFMA16(A0, B0) \
    __builtin_amdgcn_s_setprio(0); \
    __builtin_amdgcn_sched_barrier(0); \
    VM_STMT; \
    asm volatile("s_waitcnt lgkmcnt(0)" ::: "memory"); \
    __builtin_amdgcn_sched_barrier(0); \
    __builtin_amdgcn_s_barrier(); \
    RD_KS0(BN1); \
    __builtin_amdgcn_sched_barrier(0); \
    __builtin_amdgcn_s_setprio(1); \
    MFMA16(A1, B1) \
    __builtin_amdgcn_s_setprio(0); \
    __builtin_amdgcn_sched_barrier(0); \
  }while(0)

  STG_ALL(BUF0, 0);
  STG_ALL(BUF1, 1);
  vmw<6>();
  __builtin_amdgcn_s_barrier();
  RD_KS0(BUF0);

#pragma unroll 1
  for (int i = 0; i < K3; ++i){
    const int kt = i*3;
    TILE(BUF0, BUF1, STG_ALL(BUF2, kt+2), vmw<6>());
    TILE(BUF1, BUF2, STG_ALL(BUF0, kt+3), vmw<6>());
    TILE(BUF2, BUF0, STG_ALL(BUF1, kt+4), vmw<6>());
  }
  TILE(BUF0, BUF1, STG_ALL(BUF2, NTILES-2), vmw<6>());
  TILE(BUF1, BUF2, STG_ALL(BUF0, NTILES-1), vmw<6>());
  TILE(BUF2, BUF0, (void)0, vmw<0>());
  {
    RD_KS1(BUF0);
    __builtin_amdgcn_sched_barrier(0);
    __builtin_amdgcn_s_setprio(1);
    MFMA16(A0, B0)
    __builtin_amdgcn_s_setprio(0);
    __builtin_amdgcn_sched_barrier(0);
    __builtin_amdgcn_s_setprio(1);
    MFMA16(A1, B1)
    __builtin_amdgcn_s_setprio(0);
  }
#undef TILE
#undef RD_KS0
#undef RD_KS1
#undef MFMA16
#undef STG_ALL

  const int ng4 = kg*4;
#pragma unroll
  for (int mf=0; mf<4; ++mf){
    const int m = m0 + wr*64 + mf*16 + r15;
    const float wg = slotw[m];
#pragma unroll
    for (int nf=0; nf<4; ++nf){
      const int nb = n0 + wn*64 + nf*16 + ng4;
      const float4 bv = *(const float4*)&bias[(size_t)e*NT + nb];
      float q0 = (acc[mf][nf][0] + bv.x)*wg;
      float q1 = (acc[mf][nf][1] + bv.y)*wg;
      float q2 = (acc[mf][nf][2] + bv.z)*wg;
      float q3 = (acc[mf][nf][3] + bv.w)*wg;
      us4 o; o[0]=f2bf(q0); o[1]=f2bf(q1); o[2]=f2bf(q2); o[3]=f2bf(q3);
      *(us4*)&Cout[(size_t)m*NT + nb] = o;
    }
  }
}

// ---------------- combine: out[t] = Y[slot0] + Y[slot1] ----------------
__global__ __launch_bounds__(256) void combine_kernel(
    const unsigned short* __restrict__ Yb, const int* __restrict__ tok_slot,
    float* __restrict__ out)
{
  const int t = blockIdx.x;
  const int tid = threadIdx.x;
  const int s0 = tok_slot[2*t], s1 = tok_slot[2*t+1];
  const us4 a = *(const us4*)&Yb[(size_t)s0*D_MODEL + tid*4];
  const us4 b = *(const us4*)&Yb[(size_t)s1*D_MODEL + tid*4];
  float4 o;
  o.x = bf2f(a[0]) + bf2f(b[0]);
  o.y = bf2f(a[1]) + bf2f(b[1]);
  o.z = bf2f(a[2]) + bf2f(b[2]);
  o.w = bf2f(a[3]) + bf2f(b[3]);
  *(float4*)&out[(size_t)t*D_MODEL + tid*4] = o;
}

extern "C" void kernel_launch(void* const* d_in, const int* in_sizes, int n_in,
                              void* d_out, int out_size, void* d_ws, size_t ws_size,
                              hipStream_t stream)
{
  const float* x  = (const float*)d_in[0];
  const float* Wr = (const float*)d_in[1];
  const float* br = (const float*)d_in[2];
  const float* W1 = (const float*)d_in[3];
  const float* b1 = (const float*)d_in[4];
  const float* W2 = (const float*)d_in[5];
  const float* b2 = (const float*)d_in[6];
  float* out = (float*)d_out;
  char* ws = (char*)d_ws;

  const bool p256 = ws_size >= REQ_NEW;

  int*   cursors = (int*)(ws + WS_CURSORS);
  int*   padoff  = (int*)(ws + WS_PADOFF);
  int*   meta    = (int*)(ws + WS_META);
  int*   tileE   = (int*)(ws + WS_TILE_E);
  float* pp      = (float*)(ws + WS_PP);
  int*   top_e   = (int*)(ws + WS_TOP_E);
  float* top_w   = (float*)(ws + WS_TOP_W);
  int*   tok_rank= (int*)(ws + WS_TOK_RANK);
  float* slot_w  = (float*)(ws + WS_SLOT_W);
  int*   tok_slot= (int*)(ws + WS_TOK_SLOT);
  unsigned short* Xg = (unsigned short*)(ws + WS_XG);
  unsigned short* Hb = (unsigned short*)(ws + (p256 ? WS_HB_N : WS_HB_O));
  unsigned short* Wb = (unsigned short*)(ws + (p256 ? WS_WB_N : WS_WB_O));
  unsigned short* Yb = Xg;   // Xg dead after GEMM1

  hipFuncSetAttribute((const void*)moe_g256<D_MODEL, EXP_D>,
                      hipFuncAttributeMaxDynamicSharedMemorySize, 131072);
  hipFuncSetAttribute((const void*)moe_gemm_w<D_MODEL, EXP_D>,
                      hipFuncAttributeMaxDynamicSharedMemorySize, 163840);
  hipFuncSetAttribute((const void*)moe_gemm3<EXP_D, D_MODEL, MAXT128H, true>,
                      hipFuncAttributeMaxDynamicSharedMemorySize, 147456);
  hipFuncSetAttribute((const void*)moe_gemm3<EXP_D, D_MODEL, MAX_TILES, false>,
                      hipFuncAttributeMaxDynamicSharedMemorySize, 147456);

  hipMemsetAsync(ws, 0, 128, stream);   // cursors etc zero
  router_cvt_kernel<<<dim3(NTOK/4 + 2048), dim3(256), 0, stream>>>(
      x, Wr, br, top_e, top_w, pp, W1, Wb);
  scatter_kernel<<<dim3(NTOK/1024), dim3(1024), 0, stream>>>(top_e, cursors, tok_rank);
  prefix_kernel<<<dim3(1), dim3(256), 0, stream>>>((int*)ws, pp, out + (size_t)NTOK*D_MODEL,
                                                   p256 ? 8 : 7);
  gather_kernel<<<dim3(NTOK/4), dim3(256), 0, stream>>>(x, top_e, top_w, tok_rank, padoff,
                                                        tok_slot, slot_w, Xg);
  if (p256){
    moe_g256<D_MODEL, EXP_D>
        <<<dim3((EXP_D/256)*MAXT256), dim3(512), 131072, stream>>>(
        Xg, Wb, b1, Hb, tileE, meta);
    cvt_kernel<<<dim3(2048), dim3(256), 0, stream>>>(W2, Wb);
    moe_gemm3<EXP_D, D_MODEL, MAXT128H, true>
        <<<dim3((D_MODEL/256)*MAXT128H), dim3(512), 147456, stream>>>(
        Hb, Wb, b2, Yb, tileE, meta, slot_w);
  } else {
    moe_gemm_w<D_MODEL, EXP_D>
        <<<dim3((EXP_D/512)*MAX_TILES), dim3(512), 163840, stream>>>(
        Xg, Wb, b1, Hb, tileE, meta);
    cvt_kernel<<<dim3(2048), dim3(256), 0, stream>>>(W2, Wb);
    moe_gemm3<EXP_D, D_MODEL, MAX_TILES, false>
        <<<dim3((D_MODEL/256)*MAX_TILES), dim3(512), 147456, stream>>>(
        Hb, Wb, b2, Yb, tileE, meta, slot_w);
  }
  combine_kernel<<<dim3(NTOK), dim3(256), 0, stream>>>(Yb, tok_slot, out);
}